// Round 10
// baseline (44.791 us; speedup 1.0000x reference)
//
#include <hip/hip_runtime.h>
#include <math.h>

#define NB 2
#define NN 1024
#define NH 64
#define NK 8
#define ITILE 8

typedef float f32x2 __attribute__((ext_vector_type(2)));
typedef float f32x16 __attribute__((ext_vector_type(16)));
typedef _Float16 half8 __attribute__((ext_vector_type(8)));
typedef _Float16 half2t __attribute__((ext_vector_type(2)));
typedef __fp16 fp16x2 __attribute__((ext_vector_type(2)));
typedef unsigned u32x2 __attribute__((ext_vector_type(2)));

union FragU { uint32_t u[4]; uint4 q; half8 h; };
union H2U  { half2t h; fp16x2 p; uint32_t u; };
union C32U { f32x16 v; f32x2 d[8]; float f[16]; };

static __device__ __forceinline__ uint32_t pk_rne(float a, float b) {
    half2t t; t[0] = (_Float16)a; t[1] = (_Float16)b;
    H2U r; r.h = t; return r.u;
}

// lane-half exchange: w0 = [a_lo | b_lo], w2 = [a_hi | b_hi]
static __device__ __forceinline__ void half_swap(uint32_t a, uint32_t b,
                                                 uint32_t& w0, uint32_t& w2) {
#if __has_builtin(__builtin_amdgcn_permlane32_swap)
    u32x2 s = __builtin_amdgcn_permlane32_swap(a, b, false, false);
    w0 = s[0]; w2 = s[1];
#else
    const int hi = (threadIdx.x & 63) >> 5;
    uint32_t pa = __shfl_xor(a, 32), pb = __shfl_xor(b, 32);
    w0 = hi ? pb : a;
    w2 = hi ? b : pa;
#endif
}

// ---------------- prep1 ----------------
// blocks 0..7 : pt[b][n] = (x, y, cos h, sin h) f32
// block 8     : w1tab (centered W1 rows) + w2pack A2-frags (32x32x16)
__global__ void prep_kernel(const float* __restrict__ rv,
                            const float* __restrict__ W1,
                            const float* __restrict__ b1,
                            const float* __restrict__ W2,
                            float* __restrict__ pt,
                            float* __restrict__ w1tab,
                            uint4* __restrict__ w2pack) {
    const int tid = threadIdx.x;
    const int bid = blockIdx.x;
    if (bid < 8) {
        const int idx = bid * 256 + tid;  // 0..2047
        const float x0 = rv[idx*4+0], y0 = rv[idx*4+1];
        const float vx = rv[idx*4+2] - x0, vy = rv[idx*4+3] - y0;
        const float rinv = rsqrtf(fmaf(vx, vx, vy * vy));
        float4 o; o.x = x0; o.y = y0; o.z = vx * rinv; o.w = vy * rinv;
        reinterpret_cast<float4*>(pt)[idx] = o;
    } else {
        __shared__ float mean[6];
        if (tid < 5)       { float m = 0.f; for (int h = 0; h < NH; ++h) m += W1[tid*NH+h]; mean[tid] = m * (1.f/NH); }
        else if (tid == 5) { float m = 0.f; for (int h = 0; h < NH; ++h) m += b1[h];        mean[5]   = m * (1.f/NH); }
        __syncthreads();
        if (tid < NH) {
            const int h = tid;
            w1tab[h*8+0] = W1[0*NH+h]-mean[0];
            w1tab[h*8+1] = W1[1*NH+h]-mean[1];
            w1tab[h*8+2] = W1[2*NH+h]-mean[2];
            w1tab[h*8+3] = W1[3*NH+h]-mean[3];
            w1tab[h*8+4] = W1[4*NH+h]-mean[4];
            w1tab[h*8+5] = b1[h]-mean[5];
            w1tab[h*8+6] = 0.f;
            w1tab[h*8+7] = 0.f;
        }
        const int c = tid >> 6, l = tid & 63;
        const int row = l & 31;
        const int hb = 16*c + 8*(l >> 5);
        uint32_t dw[4];
        for (int t = 0; t < 4; ++t) {
            const int h0 = hb + 2*t;
            const float a = (row < 8) ? W2[h0*NK + row]     : 0.f;
            const float d = (row < 8) ? W2[(h0+1)*NK + row] : 0.f;
            dw[t] = pk_rne(a, d);
        }
        uint4 v; v.x = dw[0]; v.y = dw[1]; v.z = dw[2]; v.w = dw[3];
        w2pack[c*64 + l] = v;
    }
}

// ---------------- prep2: M(b,i) = Q~^T Q~ / 64 (21 coeffs, weights folded) ----
// One wave per (b,i); lane = h. Q~ rounded to f16 EXACTLY as the main kernel
// builds its A-fragments (RNE for qc,qs,qx,qy,w0; RTZ for cn).
// Layout (24 f32): 0..9 quad cc,cs,cx,cy,ss,sx,sy,xx,xy,yy | 10..13 lin c,s,x,y
// | 14 const | 15..18 g-lin c,s,x,y | 19 g*1 | 20 g^2.  Off-diag have x2 folded.
__global__ void prep2_kernel(const float* __restrict__ pt,
                             const float* __restrict__ w1tab,
                             float* __restrict__ Mtab) {
    const int wid  = (blockIdx.x * 256 + threadIdx.x) >> 6;  // 0..2047
    const int lane = threadIdx.x & 63;
    const int b = wid >> 10, i = wid & 1023;
    const float4 t0 = reinterpret_cast<const float4*>(w1tab)[lane*2];
    const float4 t1 = reinterpret_cast<const float4*>(w1tab)[lane*2+1];
    const float4 p  = reinterpret_cast<const float4*>(pt)[b*NN + i];
    const float x0 = p.x, y0 = p.y, ci = p.z, si = p.w;
    const float qc = fmaf(t0.y, ci,  t0.z * si);
    const float qs = fmaf(t0.y, si, -t0.z * ci);
    const float qx = fmaf(-t0.w, ci,  t1.x * si);
    const float qy = fmaf(-t0.w, si, -t1.x * ci);
    const float u1 = fmaf(x0, ci, y0 * si);
    const float u2 = fmaf(y0, ci, -x0 * si);
    const float cn = fmaf(t0.w, u1, fmaf(t1.x, u2, t1.y));
    H2U r0; r0.u = pk_rne(qc, qs);
    H2U r1; r1.u = pk_rne(qx, qy);
    H2U r2; r2.u = pk_rne(t0.x, 0.f);
    H2U r3; r3.p = __builtin_amdgcn_cvt_pkrtz(0.f, cn);
    const float q0 = (float)r0.h[0], q1 = (float)r0.h[1];
    const float q2 = (float)r1.h[0], q3 = (float)r1.h[1];
    const float q4 = (float)r2.h[0];   // col4 (pairs with g)
    const float q5 = (float)r3.h[1];   // col5 (pairs with 1)
    float v[21] = { q0*q0, q0*q1, q0*q2, q0*q3, q1*q1, q1*q2, q1*q3,
                    q2*q2, q2*q3, q3*q3,
                    q0*q5, q1*q5, q2*q5, q3*q5,
                    q5*q5,
                    q0*q4, q1*q4, q2*q4, q3*q4,
                    q4*q5,
                    q4*q4 };
#pragma unroll
    for (int t = 0; t < 21; ++t) {
        float s = v[t];
        s += __shfl_xor(s, 1);  s += __shfl_xor(s, 2);  s += __shfl_xor(s, 4);
        s += __shfl_xor(s, 8);  s += __shfl_xor(s, 16); s += __shfl_xor(s, 32);
        v[t] = s;
    }
    if (lane == 0) {
        float* Mo = Mtab + (size_t)wid * 24;
        const float w1_ = 1.f/64.f, w2_ = 2.f/64.f;
        Mo[0]  = v[0]*w1_;  Mo[1]  = v[1]*w2_;  Mo[2]  = v[2]*w2_;  Mo[3]  = v[3]*w2_;
        Mo[4]  = v[4]*w1_;  Mo[5]  = v[5]*w2_;  Mo[6]  = v[6]*w2_;
        Mo[7]  = v[7]*w1_;  Mo[8]  = v[8]*w2_;  Mo[9]  = v[9]*w1_;
        Mo[10] = v[10]*w2_; Mo[11] = v[11]*w2_; Mo[12] = v[12]*w2_; Mo[13] = v[13]*w2_;
        Mo[14] = v[14]*w1_;
        Mo[15] = v[15]*w2_; Mo[16] = v[16]*w2_; Mo[17] = v[17]*w2_; Mo[18] = v[18]*w2_;
        Mo[19] = v[19]*w2_;
        Mo[20] = v[20]*w1_;
        Mo[21] = 0.f; Mo[22] = 0.f; Mo[23] = 0.f;
    }
}

// ---------------- main ----------------
// Per wave: 32 j, ITILE i. A1-frags built in-register. Variance via the
// precomputed quadratic form (wave-uniform M row -> s_loads): NO reduction,
// NO MFMA->rsqrt dependency. inv/gamma fold overlaps MFMA1. GEMM2 as two
// independent 2-chains + vector add, b2 folded into acc init.
__global__ __launch_bounds__(256, 3) void rpe_kernel(
    const float* __restrict__ pt,
    const float* __restrict__ Mtab,
    const float* __restrict__ w1tab,
    const uint4* __restrict__ w2pack,
    const float* __restrict__ gamma,
    const float* __restrict__ beta,
    const float* __restrict__ b2,
    float* __restrict__ out) {
    const int tid  = threadIdx.x;
    const int wave = tid >> 6;
    const int lane = tid & 63;
    const int jj   = lane & 31;
    const int hi   = lane >> 5;
    const int b  = blockIdx.z;
    const int j0 = blockIdx.x * 128 + wave * 32;
    const int iBase = blockIdx.y * ITILE;

    const float4 pj = reinterpret_cast<const float4*>(pt)[b*NN + j0 + jj];
    const float xj = pj.x, yj = pj.y;
    const uint32_t d0 = pk_rne(pj.z, pj.w);
    const uint32_t d1 = pk_rne(xj, yj);
    // f16-rounded statics (must match what the MFMA consumes)
    H2U ud0, ud1; ud0.u = d0; ud1.u = d1;
    const float cj = (float)ud0.h[0], sj = (float)ud0.h[1];
    const float xv = (float)ud1.h[0], yv = (float)ud1.h[1];
    // pair products for the quadratic form (lane-static)
    const float pcc = cj*cj, pcs = cj*sj, pcx = cj*xv, pcy = cj*yv;
    const float pss = sj*sj, psx = sj*xv, psy = sj*yv;
    const float pxx = xv*xv, pxy = xv*yv, pyy = yv*yv;

    // lane-fixed centered W1 rows (zeros for hi lanes -> A hi-frags exact 0)
    float4 wA0 = {0,0,0,0}, wA1 = {0,0,0,0}, wB0 = {0,0,0,0}, wB1 = {0,0,0,0};
    if (lane < 32) {
        const float4* t4 = reinterpret_cast<const float4*>(w1tab);
        wA0 = t4[lane*2];        wA1 = t4[lane*2+1];
        wB0 = t4[(lane+32)*2];   wB1 = t4[(lane+32)*2+1];
    }
    const uint32_t w0fA = pk_rne(wA0.x, 0.f);
    const uint32_t w0fB = pk_rne(wB0.x, 0.f);

    // gamma/beta fp16 pairs: word (T,m) -> rows h0,h0+1 ; h0 = 32T+8(m>>1)+2(m&1)+4hi
    uint32_t gph[16], bph[16];
#pragma unroll
    for (int T = 0; T < 2; ++T)
#pragma unroll
        for (int m = 0; m < 8; ++m) {
            const int h0 = 32*T + 8*(m>>1) + 2*(m&1) + 4*hi;
            gph[T*8+m] = pk_rne(gamma[h0], gamma[h0+1]);
            bph[T*8+m] = pk_rne(beta[h0],  beta[h0+1]);
        }

    FragU a2[4];
#pragma unroll
    for (int c = 0; c < 4; ++c) a2[c].q = w2pack[c*64 + lane];
    float b2v[4];
#pragma unroll
    for (int r = 0; r < 4; ++r) b2v[r] = b2[4*hi + r];

    const float4* ptb = reinterpret_cast<const float4*>(pt) + b*NN + iBase;
    float4 piv = ptb[0];

    const f32x16 z16 = {0,0,0,0,0,0,0,0,0,0,0,0,0,0,0,0};
    half2t z2; z2[0] = (_Float16)0.f; z2[1] = (_Float16)0.f;
    const size_t plane = (size_t)NN * NN;
    float* op = out + (size_t)(b*NK + 4*hi)*plane + (size_t)iBase*NN + (j0 + jj);
    const float* Mbase = Mtab + (size_t)(b*NN + iBase) * 24;

    for (int ii = 0; ii < ITILE; ++ii) {
        const float x0 = piv.x, y0 = piv.y, ci = piv.z, si = piv.w;
        if (ii + 1 < ITILE) piv = ptb[ii + 1];
        const float* Mr = Mbase + ii * 24;   // wave-uniform -> s_loads

        const float u1 = fmaf(x0, ci, y0 * si);
        const float u2 = fmaf(y0, ci, -x0 * si);

        FragU qf0, qf1;
        {
            const float qc = fmaf(wA0.y, ci,  wA0.z * si);
            const float qs = fmaf(wA0.y, si, -wA0.z * ci);
            const float qx = fmaf(-wA0.w, ci,  wA1.x * si);
            const float qy = fmaf(-wA0.w, si, -wA1.x * ci);
            const float cn = fmaf(wA0.w, u1, fmaf(wA1.x, u2, wA1.y));
            qf0.u[0] = pk_rne(qc, qs); qf0.u[1] = pk_rne(qx, qy);
            H2U c16; c16.p = __builtin_amdgcn_cvt_pkrtz(0.f, cn);
            qf0.u[2] = w0fA | (c16.u & 0xFFFF0000u); qf0.u[3] = 0u;
        }
        {
            const float qc = fmaf(wB0.y, ci,  wB0.z * si);
            const float qs = fmaf(wB0.y, si, -wB0.z * ci);
            const float qx = fmaf(-wB0.w, ci,  wB1.x * si);
            const float qy = fmaf(-wB0.w, si, -wB1.x * ci);
            const float cn = fmaf(wB0.w, u1, fmaf(wB1.x, u2, wB1.y));
            qf1.u[0] = pk_rne(qc, qs); qf1.u[1] = pk_rne(qx, qy);
            H2U c16; c16.p = __builtin_amdgcn_cvt_pkrtz(0.f, cn);
            qf1.u[2] = w0fB | (c16.u & 0xFFFF0000u); qf1.u[3] = 0u;
        }

        // per-pair feature (log-dist), raw HW transcendentals
        const float dx = x0 - xj, dy = y0 - yj;
        const float dist = __builtin_amdgcn_sqrtf(fmaf(dx, dx, dy * dy));
        const float g32 = 0.69314718f * __builtin_amdgcn_logf(dist + 1e-5f);
        H2U e0; e0.p = __builtin_amdgcn_cvt_pkrtz(g32, 1.0f);
        const float g = (float)e0.h[0];   // f16-rounded, as MFMA sees it
        FragU bf; bf.u[0] = d0; bf.u[1] = d1; bf.u[2] = e0.u; bf.u[3] = 0u;

        C32U cA, cB;
        cA.v = __builtin_amdgcn_mfma_f32_32x32x16_f16(qf0.h, bf.h, z16, 0, 0, 0);
        cB.v = __builtin_amdgcn_mfma_f32_32x32x16_f16(qf1.h, bf.h, z16, 0, 0, 0);

        // variance via quadratic form (independent of MFMA results)
        float A0 = Mr[14];
        float A1 = 0.f, A2 = 0.f;
        A0 = fmaf(pcc, Mr[0], A0); A1 = fmaf(pcs, Mr[1], A1); A2 = fmaf(pcx, Mr[2], A2);
        A0 = fmaf(pcy, Mr[3], A0); A1 = fmaf(pss, Mr[4], A1); A2 = fmaf(psx, Mr[5], A2);
        A0 = fmaf(psy, Mr[6], A0); A1 = fmaf(pxx, Mr[7], A1); A2 = fmaf(pxy, Mr[8], A2);
        A0 = fmaf(pyy, Mr[9], A0); A1 = fmaf(cj, Mr[10], A1); A2 = fmaf(sj, Mr[11], A2);
        A0 = fmaf(xv, Mr[12], A0); A1 = fmaf(yv, Mr[13], A1);
        float Bg = Mr[19];
        Bg = fmaf(cj, Mr[15], Bg); Bg = fmaf(sj, Mr[16], Bg);
        Bg = fmaf(xv, Mr[17], Bg); Bg = fmaf(yv, Mr[18], Bg);
        Bg = fmaf(g, Mr[20], Bg);
        const float sq = fmaf(g, Bg, A0 + A1 + A2);
        const float inv = __builtin_amdgcn_rsqf(sq + 1e-5f);
        H2U inv2u; inv2u.p = __builtin_amdgcn_cvt_pkrtz(inv, inv);
        const half2t inv2 = inv2u.h;

        // normalize + affine + relu (packed f16); gamma*inv fold
        uint32_t yw[16];
#pragma unroll
        for (int m = 0; m < 8; ++m) {
            H2U x; x.p = __builtin_amdgcn_cvt_pkrtz(cA.d[m][0], cA.d[m][1]);
            H2U gg, bb; gg.u = gph[m]; bb.u = bph[m];
            half2t gs = gg.h * inv2;
            half2t y = __builtin_elementwise_fma(x.h, gs, bb.h);
            y = __builtin_elementwise_max(y, z2);
            H2U o; o.h = y; yw[m] = o.u;
        }
#pragma unroll
        for (int m = 0; m < 8; ++m) {
            H2U x; x.p = __builtin_amdgcn_cvt_pkrtz(cB.d[m][0], cB.d[m][1]);
            H2U gg, bb; gg.u = gph[8+m]; bb.u = bph[8+m];
            half2t gs = gg.h * inv2;
            half2t y = __builtin_elementwise_fma(x.h, gs, bb.h);
            y = __builtin_elementwise_max(y, z2);
            H2U o; o.h = y; yw[8+m] = o.u;
        }

        // GEMM2: two independent 2-chains, b2 in acc0 init
        C32U acc0, acc1;
        acc0.v = z16;
        acc0.f[0] = b2v[0]; acc0.f[1] = b2v[1]; acc0.f[2] = b2v[2]; acc0.f[3] = b2v[3];
        acc1.v = z16;
#pragma unroll
        for (int c = 0; c < 2; ++c) {
            uint32_t w0, w1, w2, w3;
            half_swap(yw[4*c + 0], yw[4*c + 2], w0, w2);
            half_swap(yw[4*c + 1], yw[4*c + 3], w1, w3);
            FragU Bf; Bf.u[0] = w0; Bf.u[1] = w1; Bf.u[2] = w2; Bf.u[3] = w3;
            acc0.v = __builtin_amdgcn_mfma_f32_32x32x16_f16(a2[c].h, Bf.h, acc0.v, 0, 0, 0);
        }
#pragma unroll
        for (int c = 2; c < 4; ++c) {
            uint32_t w0, w1, w2, w3;
            half_swap(yw[4*c + 0], yw[4*c + 2], w0, w2);
            half_swap(yw[4*c + 1], yw[4*c + 3], w1, w3);
            FragU Bf; Bf.u[0] = w0; Bf.u[1] = w1; Bf.u[2] = w2; Bf.u[3] = w3;
            acc1.v = __builtin_amdgcn_mfma_f32_32x32x16_f16(a2[c].h, Bf.h, acc1.v, 0, 0, 0);
        }

        op[0]       = acc0.f[0] + acc1.f[0];
        op[plane]   = acc0.f[1] + acc1.f[1];
        op[2*plane] = acc0.f[2] + acc1.f[2];
        op[3*plane] = acc0.f[3] + acc1.f[3];
        op += NN;
    }
}

extern "C" void kernel_launch(void* const* d_in, const int* in_sizes, int n_in,
                              void* d_out, int out_size, void* d_ws, size_t ws_size,
                              hipStream_t stream) {
    const float* rv    = (const float*)d_in[0];
    const float* W1    = (const float*)d_in[1];
    const float* b1    = (const float*)d_in[2];
    const float* gamma = (const float*)d_in[3];
    const float* beta  = (const float*)d_in[4];
    const float* W2    = (const float*)d_in[5];
    const float* b2    = (const float*)d_in[6];
    float* out = (float*)d_out;

    float* ws = (float*)d_ws;
    float* pt     = ws;                        // 8192 f32 (32 KB)
    float* w1tab  = ws + 8192;                 // 512 f32 (2 KB)
    uint4* w2pack = (uint4*)(ws + 8704);       // 1024 f32 (4 KB)
    float* Mtab   = ws + 9728;                 // 2048*24 f32 (192 KB)

    prep_kernel<<<9, 256, 0, stream>>>(rv, W1, b1, W2, pt, w1tab, w2pack);
    prep2_kernel<<<512, 256, 0, stream>>>(pt, w1tab, Mtab);

    dim3 grid(NN / 128, NN / ITILE, NB);
    rpe_kernel<<<grid, 256, 0, stream>>>(pt, Mtab, w1tab, w2pack, gamma, beta, b2, out);
}

// Round 11
// 39.231 us; speedup vs baseline: 1.1417x; 1.1417x over previous
//
#include <hip/hip_runtime.h>
#include <math.h>

#define NB 2
#define NN 1024
#define NH 64
#define NK 8
#define ITILE 8

typedef float f32x2 __attribute__((ext_vector_type(2)));
typedef float f32x16 __attribute__((ext_vector_type(16)));
typedef _Float16 half8 __attribute__((ext_vector_type(8)));
typedef _Float16 half2t __attribute__((ext_vector_type(2)));
typedef __fp16 fp16x2 __attribute__((ext_vector_type(2)));
typedef unsigned u32x2 __attribute__((ext_vector_type(2)));

union FragU { uint32_t u[4]; uint4 q; half8 h; };
union H2U  { half2t h; fp16x2 p; uint32_t u; };
union C32U { f32x16 v; f32x2 d[8]; float f[16]; };

static __device__ __forceinline__ uint32_t pk_rne(float a, float b) {
    half2t t; t[0] = (_Float16)a; t[1] = (_Float16)b;
    H2U r; r.h = t; return r.u;
}

// lane-half exchange: w0 = [a_lo | b_lo], w2 = [a_hi | b_hi]
static __device__ __forceinline__ void half_swap(uint32_t a, uint32_t b,
                                                 uint32_t& w0, uint32_t& w2) {
#if __has_builtin(__builtin_amdgcn_permlane32_swap)
    u32x2 s = __builtin_amdgcn_permlane32_swap(a, b, false, false);
    w0 = s[0]; w2 = s[1];
#else
    const int hi = (threadIdx.x & 63) >> 5;
    uint32_t pa = __shfl_xor(a, 32), pb = __shfl_xor(b, 32);
    w0 = hi ? pb : a;
    w2 = hi ? b : pa;
#endif
}

// cross-half sum without DS: own + partner(lane^32), pure VALU
static __device__ __forceinline__ float wave_sum_half(float v) {
#if __has_builtin(__builtin_amdgcn_permlane32_swap)
    union { float f; uint32_t u; } a, r0, r1;
    a.f = v;
    u32x2 s = __builtin_amdgcn_permlane32_swap(a.u, a.u, false, false);
    r0.u = s[0]; r1.u = s[1];
    return r0.f + r1.f;
#else
    return v + __shfl_xor(v, 32);
#endif
}

// ---------------- prep ----------------
// blocks 0..7 : pt[b][n] = (x, y, cos h, sin h) f32
// block 8     : w1tab (centered W1 rows); fast-flag (beta==0 && gamma>=0);
//               w2pack A2-frags (32x32x16) with gamma folded when fast;
//               gbtab f16 gamma/beta pairs for the (never-hit) fallback.
__global__ void prep_kernel(const float* __restrict__ rv,
                            const float* __restrict__ W1,
                            const float* __restrict__ b1,
                            const float* __restrict__ W2,
                            const float* __restrict__ gamma,
                            const float* __restrict__ beta,
                            float* __restrict__ pt,
                            float* __restrict__ w1tab,
                            uint4* __restrict__ w2pack,
                            uint2* __restrict__ gbtab,
                            int* __restrict__ flagp) {
    const int tid = threadIdx.x;
    const int bid = blockIdx.x;
    if (bid < 8) {
        const int idx = bid * 256 + tid;  // 0..2047
        const float x0 = rv[idx*4+0], y0 = rv[idx*4+1];
        const float vx = rv[idx*4+2] - x0, vy = rv[idx*4+3] - y0;
        const float rinv = rsqrtf(fmaf(vx, vx, vy * vy));
        float4 o; o.x = x0; o.y = y0; o.z = vx * rinv; o.w = vy * rinv;
        reinterpret_cast<float4*>(pt)[idx] = o;
    } else {
        __shared__ float mean[6];
        __shared__ int oks;
        if (tid == 0) oks = 1;
        if (tid < 5)       { float m = 0.f; for (int h = 0; h < NH; ++h) m += W1[tid*NH+h]; mean[tid] = m * (1.f/NH); }
        else if (tid == 5) { float m = 0.f; for (int h = 0; h < NH; ++h) m += b1[h];        mean[5]   = m * (1.f/NH); }
        __syncthreads();
        if (tid < NH) {
            const int h = tid;
            w1tab[h*8+0] = W1[0*NH+h]-mean[0];
            w1tab[h*8+1] = W1[1*NH+h]-mean[1];
            w1tab[h*8+2] = W1[2*NH+h]-mean[2];
            w1tab[h*8+3] = W1[3*NH+h]-mean[3];
            w1tab[h*8+4] = W1[4*NH+h]-mean[4];
            w1tab[h*8+5] = b1[h]-mean[5];
            w1tab[h*8+6] = 0.f;
            w1tab[h*8+7] = 0.f;
            if (!(beta[h] == 0.f && gamma[h] >= 0.f)) atomicAnd(&oks, 0);
        }
        __syncthreads();
        const int fast = oks;
        if (tid == 0) *flagp = fast;
        // w2pack: 4 chunks x 64 lanes; gamma folded when fast
        {
            const int c = tid >> 6, l = tid & 63;
            const int row = l & 31;
            const int hb = 16*c + 8*(l >> 5);
            uint32_t dw[4];
            for (int t = 0; t < 4; ++t) {
                const int h0 = hb + 2*t;
                const float gA = fast ? gamma[h0]   : 1.f;
                const float gB = fast ? gamma[h0+1] : 1.f;
                const float a = (row < 8) ? W2[h0*NK + row] * gA     : 0.f;
                const float d = (row < 8) ? W2[(h0+1)*NK + row] * gB : 0.f;
                dw[t] = pk_rne(a, d);
            }
            uint4 v; v.x = dw[0]; v.y = dw[1]; v.z = dw[2]; v.w = dw[3];
            w2pack[c*64 + l] = v;
        }
        // gbtab for fallback: [hi][16] of {gph, bph}
        if (tid < 32) {
            const int hig = tid >> 4, m16 = tid & 15;
            const int T = m16 >> 3, m = m16 & 7;
            const int h0 = 32*T + 8*(m>>1) + 2*(m&1) + 4*hig;
            uint2 gb;
            gb.x = pk_rne(gamma[h0], gamma[h0+1]);
            gb.y = pk_rne(beta[h0],  beta[h0+1]);
            gbtab[hig*16 + m16] = gb;
        }
    }
}

// sumsq of one 32x32 C pair (mu==0 exact by pre-centering)
#define SUMSQ(cA, cB, sqv) { \
    f32x2 q0 = cA.d[0]*cA.d[0], q1 = cA.d[1]*cA.d[1], q2 = cA.d[2]*cA.d[2], q3 = cA.d[3]*cA.d[3]; \
    q0 = __builtin_elementwise_fma(cA.d[4], cA.d[4], q0); \
    q1 = __builtin_elementwise_fma(cA.d[5], cA.d[5], q1); \
    q2 = __builtin_elementwise_fma(cA.d[6], cA.d[6], q2); \
    q3 = __builtin_elementwise_fma(cA.d[7], cA.d[7], q3); \
    q0 = __builtin_elementwise_fma(cB.d[0], cB.d[0], q0); \
    q1 = __builtin_elementwise_fma(cB.d[1], cB.d[1], q1); \
    q2 = __builtin_elementwise_fma(cB.d[2], cB.d[2], q2); \
    q3 = __builtin_elementwise_fma(cB.d[3], cB.d[3], q3); \
    q0 = __builtin_elementwise_fma(cB.d[4], cB.d[4], q0); \
    q1 = __builtin_elementwise_fma(cB.d[5], cB.d[5], q1); \
    q2 = __builtin_elementwise_fma(cB.d[6], cB.d[6], q2); \
    q3 = __builtin_elementwise_fma(cB.d[7], cB.d[7], q3); \
    q0 += q1; q2 += q3; q0 += q2; \
    sqv = q0[0] + q0[1]; }

// ---------------- main ----------------
// Per wave: 32 j, ITILE i. A1-frags in-register. FAST PATH (beta==0,
// gamma>=0, gamma folded into W2): relu(x)/sigma == relu(x/sigma) ->
// GEMM2 consumes relu(raw x) in f16, INDEPENDENT of inv; the rsqrt chain
// (sumsq -> permlane -> rsqrt) overlaps cvt/swap/MFMA2 and joins only at
// the final 4 fma. Critical path ~halved vs normalize-before-GEMM2.
__global__ __launch_bounds__(256, 3) void rpe_kernel(
    const float* __restrict__ pt,
    const float* __restrict__ w1tab,
    const uint4* __restrict__ w2pack,
    const uint2* __restrict__ gbtab,
    const int* __restrict__ flagp,
    const float* __restrict__ b2,
    float* __restrict__ out) {
    const int tid  = threadIdx.x;
    const int wave = tid >> 6;
    const int lane = tid & 63;
    const int jj   = lane & 31;
    const int hi   = lane >> 5;
    const int b  = blockIdx.z;
    const int j0 = blockIdx.x * 128 + wave * 32;
    const int iBase = blockIdx.y * ITILE;
    const int fast = *flagp;

    const float4 pj = reinterpret_cast<const float4*>(pt)[b*NN + j0 + jj];
    const float xj = pj.x, yj = pj.y;
    const uint32_t d0 = pk_rne(pj.z, pj.w);
    const uint32_t d1 = pk_rne(xj, yj);

    // lane-fixed centered W1 rows (zeros for hi lanes -> A k>=8 exact 0)
    float4 wA0 = {0,0,0,0}, wA1 = {0,0,0,0}, wB0 = {0,0,0,0}, wB1 = {0,0,0,0};
    if (lane < 32) {
        const float4* t4 = reinterpret_cast<const float4*>(w1tab);
        wA0 = t4[lane*2];        wA1 = t4[lane*2+1];
        wB0 = t4[(lane+32)*2];   wB1 = t4[(lane+32)*2+1];
    }
    const uint32_t w0fA = pk_rne(wA0.x, 0.f);
    const uint32_t w0fB = pk_rne(wB0.x, 0.f);

    FragU a2[4];
#pragma unroll
    for (int c = 0; c < 4; ++c) a2[c].q = w2pack[c*64 + lane];
    float b2v[4];
#pragma unroll
    for (int r = 0; r < 4; ++r) b2v[r] = b2[4*hi + r];

    const float4* ptb = reinterpret_cast<const float4*>(pt) + b*NN + iBase;
    float4 piv = ptb[0];

    const f32x16 z16 = {0,0,0,0,0,0,0,0,0,0,0,0,0,0,0,0};
    const f32x2 z2f = {0.f, 0.f};
    half2t z2h; z2h[0] = (_Float16)0.f; z2h[1] = (_Float16)0.f;
    const size_t plane = (size_t)NN * NN;
    float* op = out + (size_t)(b*NK + 4*hi)*plane + (size_t)iBase*NN + (j0 + jj);

    for (int ii = 0; ii < ITILE; ++ii) {
        const float x0 = piv.x, y0 = piv.y, ci = piv.z, si = piv.w;
        if (ii + 1 < ITILE) piv = ptb[ii + 1];

        const float u1 = fmaf(x0, ci, y0 * si);
        const float u2 = fmaf(y0, ci, -x0 * si);

        FragU qf0, qf1;
        {
            const float qc = fmaf(wA0.y, ci,  wA0.z * si);
            const float qs = fmaf(wA0.y, si, -wA0.z * ci);
            const float qx = fmaf(-wA0.w, ci,  wA1.x * si);
            const float qy = fmaf(-wA0.w, si, -wA1.x * ci);
            const float cn = fmaf(wA0.w, u1, fmaf(wA1.x, u2, wA1.y));
            qf0.u[0] = pk_rne(qc, qs); qf0.u[1] = pk_rne(qx, qy);
            H2U c16; c16.p = __builtin_amdgcn_cvt_pkrtz(0.f, cn);
            qf0.u[2] = w0fA | (c16.u & 0xFFFF0000u); qf0.u[3] = 0u;
        }
        {
            const float qc = fmaf(wB0.y, ci,  wB0.z * si);
            const float qs = fmaf(wB0.y, si, -wB0.z * ci);
            const float qx = fmaf(-wB0.w, ci,  wB1.x * si);
            const float qy = fmaf(-wB0.w, si, -wB1.x * ci);
            const float cn = fmaf(wB0.w, u1, fmaf(wB1.x, u2, wB1.y));
            qf1.u[0] = pk_rne(qc, qs); qf1.u[1] = pk_rne(qx, qy);
            H2U c16; c16.p = __builtin_amdgcn_cvt_pkrtz(0.f, cn);
            qf1.u[2] = w0fB | (c16.u & 0xFFFF0000u); qf1.u[3] = 0u;
        }

        // per-pair feature (log-dist)
        const float dx = x0 - xj, dy = y0 - yj;
        const float dist = __builtin_amdgcn_sqrtf(fmaf(dx, dx, dy * dy));
        const float g32 = 0.69314718f * __builtin_amdgcn_logf(dist + 1e-5f);
        H2U e0; e0.p = __builtin_amdgcn_cvt_pkrtz(g32, 1.0f);
        FragU bf; bf.u[0] = d0; bf.u[1] = d1; bf.u[2] = e0.u; bf.u[3] = 0u;

        C32U cA, cB;
        cA.v = __builtin_amdgcn_mfma_f32_32x32x16_f16(qf0.h, bf.h, z16, 0, 0, 0);
        cB.v = __builtin_amdgcn_mfma_f32_32x32x16_f16(qf1.h, bf.h, z16, 0, 0, 0);

        // variance chain (off the MFMA2 critical path in fast mode)
        float sq;
        SUMSQ(cA, cB, sq)
        sq = wave_sum_half(sq);
        const float inv = __builtin_amdgcn_rsqf(fmaf(sq, 1.f/64.f, 1e-5f));

        uint32_t yw[16];
        float invf;
        if (fast) {
            // relu in f32, cvt to f16 — independent of inv
#pragma unroll
            for (int m = 0; m < 8; ++m) {
                f32x2 r = __builtin_elementwise_max(cA.d[m], z2f);
                H2U t; t.p = __builtin_amdgcn_cvt_pkrtz(r[0], r[1]);
                yw[m] = t.u;
            }
#pragma unroll
            for (int m = 0; m < 8; ++m) {
                f32x2 r = __builtin_elementwise_max(cB.d[m], z2f);
                H2U t; t.p = __builtin_amdgcn_cvt_pkrtz(r[0], r[1]);
                yw[8+m] = t.u;
            }
            invf = inv;
        } else {
            // general fallback: full normalize (gamma/beta from gbtab)
            H2U inv2u; inv2u.p = __builtin_amdgcn_cvt_pkrtz(inv, inv);
            const half2t inv2 = inv2u.h;
#pragma unroll
            for (int m = 0; m < 16; ++m) {
                const f32x2 src = (m < 8) ? cA.d[m] : cB.d[m - 8];
                uint2 gb = gbtab[hi*16 + m];
                H2U x; x.p = __builtin_amdgcn_cvt_pkrtz(src[0], src[1]);
                H2U gg, bb; gg.u = gb.x; bb.u = gb.y;
                half2t gs = gg.h * inv2;
                half2t y = __builtin_elementwise_fma(x.h, gs, bb.h);
                y = __builtin_elementwise_max(y, z2h);
                H2U o; o.h = y; yw[m] = o.u;
            }
            invf = 1.f;
        }

        // GEMM2: two independent 2-chains
        C32U acc0, acc1;
        acc0.v = z16; acc1.v = z16;
#pragma unroll
        for (int c = 0; c < 2; ++c) {
            uint32_t w0, w1, w2, w3;
            half_swap(yw[4*c + 0], yw[4*c + 2], w0, w2);
            half_swap(yw[4*c + 1], yw[4*c + 3], w1, w3);
            FragU Bf; Bf.u[0] = w0; Bf.u[1] = w1; Bf.u[2] = w2; Bf.u[3] = w3;
            acc0.v = __builtin_amdgcn_mfma_f32_32x32x16_f16(a2[c].h, Bf.h, acc0.v, 0, 0, 0);
        }
#pragma unroll
        for (int c = 2; c < 4; ++c) {
            uint32_t w0, w1, w2, w3;
            half_swap(yw[4*c + 0], yw[4*c + 2], w0, w2);
            half_swap(yw[4*c + 1], yw[4*c + 3], w1, w3);
            FragU Bf; Bf.u[0] = w0; Bf.u[1] = w1; Bf.u[2] = w2; Bf.u[3] = w3;
            acc1.v = __builtin_amdgcn_mfma_f32_32x32x16_f16(a2[c].h, Bf.h, acc1.v, 0, 0, 0);
        }

        op[0]       = fmaf(acc0.f[0] + acc1.f[0], invf, b2v[0]);
        op[plane]   = fmaf(acc0.f[1] + acc1.f[1], invf, b2v[1]);
        op[2*plane] = fmaf(acc0.f[2] + acc1.f[2], invf, b2v[2]);
        op[3*plane] = fmaf(acc0.f[3] + acc1.f[3], invf, b2v[3]);
        op += NN;
    }
}

extern "C" void kernel_launch(void* const* d_in, const int* in_sizes, int n_in,
                              void* d_out, int out_size, void* d_ws, size_t ws_size,
                              hipStream_t stream) {
    const float* rv    = (const float*)d_in[0];
    const float* W1    = (const float*)d_in[1];
    const float* b1    = (const float*)d_in[2];
    const float* gamma = (const float*)d_in[3];
    const float* beta  = (const float*)d_in[4];
    const float* W2    = (const float*)d_in[5];
    const float* b2    = (const float*)d_in[6];
    float* out = (float*)d_out;

    float* ws = (float*)d_ws;
    float* pt     = ws;                        // 8192 f32 (32 KB)
    float* w1tab  = ws + 8192;                 // 512 f32 (2 KB)
    uint4* w2pack = (uint4*)(ws + 8704);       // 1024 f32 (4 KB)
    uint2* gbtab  = (uint2*)(ws + 9728);       // 64 f32 (256 B)
    int*   flagp  = (int*)(ws + 9792);

    prep_kernel<<<9, 256, 0, stream>>>(rv, W1, b1, W2, gamma, beta,
                                       pt, w1tab, w2pack, gbtab, flagp);

    dim3 grid(NN / 128, NN / ITILE, NB);
    rpe_kernel<<<grid, 256, 0, stream>>>(pt, w1tab, w2pack, gbtab, flagp, b2, out);
}

// Round 12
// 31.983 us; speedup vs baseline: 1.4005x; 1.2266x over previous
//
#include <hip/hip_runtime.h>
#include <math.h>

#define NB 2
#define NN 1024
#define NH 64
#define NK 8
#define ITILE 8

typedef float f32x2 __attribute__((ext_vector_type(2)));
typedef float f32x16 __attribute__((ext_vector_type(16)));
typedef _Float16 half8 __attribute__((ext_vector_type(8)));
typedef _Float16 half2t __attribute__((ext_vector_type(2)));
typedef __fp16 fp16x2 __attribute__((ext_vector_type(2)));
typedef unsigned u32x2 __attribute__((ext_vector_type(2)));

union FragU { uint32_t u[4]; uint4 q; half8 h; };
union H2U  { half2t h; fp16x2 p; uint32_t u; };
union C32U { f32x16 v; f32x2 d[8]; float f[16]; };

static __device__ __forceinline__ uint32_t pk_rne(float a, float b) {
    half2t t; t[0] = (_Float16)a; t[1] = (_Float16)b;
    H2U r; r.h = t; return r.u;
}

// lane-half exchange: w0 = [a_lo | b_lo], w2 = [a_hi | b_hi]
static __device__ __forceinline__ void half_swap(uint32_t a, uint32_t b,
                                                 uint32_t& w0, uint32_t& w2) {
#if __has_builtin(__builtin_amdgcn_permlane32_swap)
    u32x2 s = __builtin_amdgcn_permlane32_swap(a, b, false, false);
    w0 = s[0]; w2 = s[1];
#else
    const int hi = (threadIdx.x & 63) >> 5;
    uint32_t pa = __shfl_xor(a, 32), pb = __shfl_xor(b, 32);
    w0 = hi ? pb : a;
    w2 = hi ? b : pa;
#endif
}

// cross-half sum without DS: own + partner(lane^32), pure VALU
static __device__ __forceinline__ float wave_sum_half(float v) {
#if __has_builtin(__builtin_amdgcn_permlane32_swap)
    union { float f; uint32_t u; } a, r0, r1;
    a.f = v;
    u32x2 s = __builtin_amdgcn_permlane32_swap(a.u, a.u, false, false);
    r0.u = s[0]; r1.u = s[1];
    return r0.f + r1.f;
#else
    return v + __shfl_xor(v, 32);
#endif
}

// ---------------- prep ----------------
__global__ void prep_kernel(const float* __restrict__ rv,
                            const float* __restrict__ W1,
                            const float* __restrict__ b1,
                            const float* __restrict__ W2,
                            const float* __restrict__ gamma,
                            const float* __restrict__ beta,
                            float* __restrict__ pt,
                            float* __restrict__ w1tab,
                            uint4* __restrict__ w2pack,
                            uint2* __restrict__ gbtab,
                            int* __restrict__ flagp) {
    const int tid = threadIdx.x;
    const int bid = blockIdx.x;
    if (bid < 8) {
        const int idx = bid * 256 + tid;  // 0..2047
        const float x0 = rv[idx*4+0], y0 = rv[idx*4+1];
        const float vx = rv[idx*4+2] - x0, vy = rv[idx*4+3] - y0;
        const float rinv = rsqrtf(fmaf(vx, vx, vy * vy));
        float4 o; o.x = x0; o.y = y0; o.z = vx * rinv; o.w = vy * rinv;
        reinterpret_cast<float4*>(pt)[idx] = o;
    } else {
        __shared__ float mean[6];
        __shared__ int oks;
        if (tid == 0) oks = 1;
        if (tid < 5)       { float m = 0.f; for (int h = 0; h < NH; ++h) m += W1[tid*NH+h]; mean[tid] = m * (1.f/NH); }
        else if (tid == 5) { float m = 0.f; for (int h = 0; h < NH; ++h) m += b1[h];        mean[5]   = m * (1.f/NH); }
        __syncthreads();
        if (tid < NH) {
            const int h = tid;
            w1tab[h*8+0] = W1[0*NH+h]-mean[0];
            w1tab[h*8+1] = W1[1*NH+h]-mean[1];
            w1tab[h*8+2] = W1[2*NH+h]-mean[2];
            w1tab[h*8+3] = W1[3*NH+h]-mean[3];
            w1tab[h*8+4] = W1[4*NH+h]-mean[4];
            w1tab[h*8+5] = b1[h]-mean[5];
            w1tab[h*8+6] = 0.f;
            w1tab[h*8+7] = 0.f;
            if (!(beta[h] == 0.f && gamma[h] >= 0.f)) atomicAnd(&oks, 0);
        }
        __syncthreads();
        const int fast = oks;
        if (tid == 0) *flagp = fast;
        {
            const int c = tid >> 6, l = tid & 63;
            const int row = l & 31;
            const int hb = 16*c + 8*(l >> 5);
            uint32_t dw[4];
            for (int t = 0; t < 4; ++t) {
                const int h0 = hb + 2*t;
                const float gA = fast ? gamma[h0]   : 1.f;
                const float gB = fast ? gamma[h0+1] : 1.f;
                const float a = (row < 8) ? W2[h0*NK + row] * gA     : 0.f;
                const float d = (row < 8) ? W2[(h0+1)*NK + row] * gB : 0.f;
                dw[t] = pk_rne(a, d);
            }
            uint4 v; v.x = dw[0]; v.y = dw[1]; v.z = dw[2]; v.w = dw[3];
            w2pack[c*64 + l] = v;
        }
        if (tid < 32) {
            const int hig = tid >> 4, m16 = tid & 15;
            const int T = m16 >> 3, m = m16 & 7;
            const int h0 = 32*T + 8*(m>>1) + 2*(m&1) + 4*hig;
            uint2 gb;
            gb.x = pk_rne(gamma[h0], gamma[h0+1]);
            gb.y = pk_rne(beta[h0],  beta[h0+1]);
            gbtab[hig*16 + m16] = gb;
        }
    }
}

// sumsq of one 32x32 C pair (mu==0 exact by pre-centering)
#define SUMSQ(cA, cB, sqv) { \
    f32x2 q0 = cA.d[0]*cA.d[0], q1 = cA.d[1]*cA.d[1], q2 = cA.d[2]*cA.d[2], q3 = cA.d[3]*cA.d[3]; \
    q0 = __builtin_elementwise_fma(cA.d[4], cA.d[4], q0); \
    q1 = __builtin_elementwise_fma(cA.d[5], cA.d[5], q1); \
    q2 = __builtin_elementwise_fma(cA.d[6], cA.d[6], q2); \
    q3 = __builtin_elementwise_fma(cA.d[7], cA.d[7], q3); \
    q0 = __builtin_elementwise_fma(cB.d[0], cB.d[0], q0); \
    q1 = __builtin_elementwise_fma(cB.d[1], cB.d[1], q1); \
    q2 = __builtin_elementwise_fma(cB.d[2], cB.d[2], q2); \
    q3 = __builtin_elementwise_fma(cB.d[3], cB.d[3], q3); \
    q0 = __builtin_elementwise_fma(cB.d[4], cB.d[4], q0); \
    q1 = __builtin_elementwise_fma(cB.d[5], cB.d[5], q1); \
    q2 = __builtin_elementwise_fma(cB.d[6], cB.d[6], q2); \
    q3 = __builtin_elementwise_fma(cB.d[7], cB.d[7], q3); \
    q0 += q1; q2 += q3; q0 += q2; \
    sqv = q0[0] + q0[1]; }

// ---------------- main ----------------
// Phase 0: all 256 threads cooperatively build the block's 16 A1-fragment
// sets (8 i x 2 tiles) ONCE into LDS (hi-slots zeroed -> clean loop reads).
// Loop (fast path): 2 ds_read_b128 + feature + 2 MFMA1 + sumsq/rsqrt chain
// (off critical path) + cvt_pkrtz + pk_max_f16 relu + permlane swaps +
// 4 MFMA2 + 1/sigma at epilogue.
__global__ __launch_bounds__(256, 4) void rpe_kernel(
    const float* __restrict__ pt,
    const float* __restrict__ w1tab,
    const uint4* __restrict__ w2pack,
    const uint2* __restrict__ gbtab,
    const int* __restrict__ flagp,
    const float* __restrict__ b2,
    float* __restrict__ out) {
    __shared__ uint4 qlds[ITILE * 2 * 64];   // 16 KB
    const int tid  = threadIdx.x;
    const int wave = tid >> 6;
    const int lane = tid & 63;
    const int jj   = lane & 31;
    const int hi   = lane >> 5;
    const int b  = blockIdx.z;
    const int j0 = blockIdx.x * 128 + wave * 32;
    const int iBase = blockIdx.y * ITILE;

    const float4* pt4 = reinterpret_cast<const float4*>(pt);
    const float4* ptb = pt4 + b*NN + iBase;

    // ---- phase 0: cooperative A1-frag build ----
    {
        const int it = tid >> 5;         // i offset 0..7
        const int sl = tid & 31;         // row slot 0..31
        const float4 p = ptb[it];
        const float x0 = p.x, y0 = p.y, ci = p.z, si = p.w;
        const float u1 = fmaf(x0, ci, y0 * si);
        const float u2 = fmaf(y0, ci, -x0 * si);
        const float4* t4 = reinterpret_cast<const float4*>(w1tab);
#pragma unroll
        for (int T = 0; T < 2; ++T) {
            const int h = 32*T + sl;
            const float4 ra = t4[h*2];
            const float4 rb = t4[h*2+1];
            const float qc = fmaf(ra.y, ci,  ra.z * si);
            const float qs = fmaf(ra.y, si, -ra.z * ci);
            const float qx = fmaf(-ra.w, ci,  rb.x * si);
            const float qy = fmaf(-ra.w, si, -rb.x * ci);
            const float cn = fmaf(ra.w, u1, fmaf(rb.x, u2, rb.y));
            H2U a_, b_, c_;
            a_.p = __builtin_amdgcn_cvt_pkrtz(qc, qs);
            b_.p = __builtin_amdgcn_cvt_pkrtz(qx, qy);
            c_.p = __builtin_amdgcn_cvt_pkrtz(ra.x, cn);
            uint4 v; v.x = a_.u; v.y = b_.u; v.z = c_.u; v.w = 0u;
            qlds[(it*2+T)*64 + sl]      = v;
            qlds[(it*2+T)*64 + 32 + sl] = make_uint4(0,0,0,0);  // hi k-slots zero
        }
    }
    __syncthreads();

    const float4 pj = pt4[b*NN + j0 + jj];
    const float xj = pj.x, yj = pj.y;
    H2U d0u, d1u;
    d0u.p = __builtin_amdgcn_cvt_pkrtz(pj.z, pj.w);
    d1u.p = __builtin_amdgcn_cvt_pkrtz(xj, yj);
    const uint32_t d0 = d0u.u, d1 = d1u.u;

    FragU a2[4];
#pragma unroll
    for (int c = 0; c < 4; ++c) a2[c].q = w2pack[c*64 + lane];
    float b2v[4];
#pragma unroll
    for (int r = 0; r < 4; ++r) b2v[r] = b2[4*hi + r];

    const f32x16 z16 = {0,0,0,0,0,0,0,0,0,0,0,0,0,0,0,0};
    half2t z2h; z2h[0] = (_Float16)0.f; z2h[1] = (_Float16)0.f;
    const size_t plane = (size_t)NN * NN;
    float* o0 = out + (size_t)(b*NK + 4*hi)*plane + (size_t)iBase*NN + (j0 + jj);
    float* o1 = o0 + plane;
    float* o2 = o0 + 2*plane;
    float* o3 = o0 + 3*plane;

    const int fast = *flagp;

    if (fast) {
        for (int ii = 0; ii < ITILE; ++ii) {
            FragU qf0, qf1;
            qf0.q = qlds[(ii*2+0)*64 + lane];
            qf1.q = qlds[(ii*2+1)*64 + lane];
            const float4 piv = ptb[ii];

            const float dx = piv.x - xj, dy = piv.y - yj;
            const float dist = __builtin_amdgcn_sqrtf(fmaf(dx, dx, dy * dy));
            const float g32 = 0.69314718f * __builtin_amdgcn_logf(dist + 1e-5f);
            H2U e0; e0.p = __builtin_amdgcn_cvt_pkrtz(g32, 1.0f);
            FragU bf; bf.u[0] = d0; bf.u[1] = d1; bf.u[2] = e0.u; bf.u[3] = 0u;

            C32U cA, cB;
            cA.v = __builtin_amdgcn_mfma_f32_32x32x16_f16(qf0.h, bf.h, z16, 0, 0, 0);
            cB.v = __builtin_amdgcn_mfma_f32_32x32x16_f16(qf1.h, bf.h, z16, 0, 0, 0);

            float sq;
            SUMSQ(cA, cB, sq)
            sq = wave_sum_half(sq);
            const float inv = __builtin_amdgcn_rsqf(fmaf(sq, 1.f/64.f, 1e-5f));

            // pack then relu in packed f16 (independent of inv)
            uint32_t yw[16];
#pragma unroll
            for (int m = 0; m < 8; ++m) {
                H2U t; t.p = __builtin_amdgcn_cvt_pkrtz(cA.d[m][0], cA.d[m][1]);
                half2t r = __builtin_elementwise_max(t.h, z2h);
                H2U o; o.h = r; yw[m] = o.u;
            }
#pragma unroll
            for (int m = 0; m < 8; ++m) {
                H2U t; t.p = __builtin_amdgcn_cvt_pkrtz(cB.d[m][0], cB.d[m][1]);
                half2t r = __builtin_elementwise_max(t.h, z2h);
                H2U o; o.h = r; yw[8+m] = o.u;
            }

            C32U acc0, acc1;
            acc0.v = z16; acc1.v = z16;
#pragma unroll
            for (int c = 0; c < 2; ++c) {
                uint32_t w0, w1, w2, w3;
                half_swap(yw[4*c + 0], yw[4*c + 2], w0, w2);
                half_swap(yw[4*c + 1], yw[4*c + 3], w1, w3);
                FragU Bf; Bf.u[0] = w0; Bf.u[1] = w1; Bf.u[2] = w2; Bf.u[3] = w3;
                acc0.v = __builtin_amdgcn_mfma_f32_32x32x16_f16(a2[c].h, Bf.h, acc0.v, 0, 0, 0);
            }
#pragma unroll
            for (int c = 2; c < 4; ++c) {
                uint32_t w0, w1, w2, w3;
                half_swap(yw[4*c + 0], yw[4*c + 2], w0, w2);
                half_swap(yw[4*c + 1], yw[4*c + 3], w1, w3);
                FragU Bf; Bf.u[0] = w0; Bf.u[1] = w1; Bf.u[2] = w2; Bf.u[3] = w3;
                acc1.v = __builtin_amdgcn_mfma_f32_32x32x16_f16(a2[c].h, Bf.h, acc1.v, 0, 0, 0);
            }

            o0[0] = fmaf(acc0.f[0] + acc1.f[0], inv, b2v[0]);
            o1[0] = fmaf(acc0.f[1] + acc1.f[1], inv, b2v[1]);
            o2[0] = fmaf(acc0.f[2] + acc1.f[2], inv, b2v[2]);
            o3[0] = fmaf(acc0.f[3] + acc1.f[3], inv, b2v[3]);
            o0 += NN; o1 += NN; o2 += NN; o3 += NN;
        }
    } else {
        // general fallback: full normalize with gamma/beta
        for (int ii = 0; ii < ITILE; ++ii) {
            FragU qf0, qf1;
            qf0.q = qlds[(ii*2+0)*64 + lane];
            qf1.q = qlds[(ii*2+1)*64 + lane];
            const float4 piv = ptb[ii];

            const float dx = piv.x - xj, dy = piv.y - yj;
            const float dist = __builtin_amdgcn_sqrtf(fmaf(dx, dx, dy * dy));
            const float g32 = 0.69314718f * __builtin_amdgcn_logf(dist + 1e-5f);
            H2U e0; e0.p = __builtin_amdgcn_cvt_pkrtz(g32, 1.0f);
            FragU bf; bf.u[0] = d0; bf.u[1] = d1; bf.u[2] = e0.u; bf.u[3] = 0u;

            C32U cA, cB;
            cA.v = __builtin_amdgcn_mfma_f32_32x32x16_f16(qf0.h, bf.h, z16, 0, 0, 0);
            cB.v = __builtin_amdgcn_mfma_f32_32x32x16_f16(qf1.h, bf.h, z16, 0, 0, 0);

            float sq;
            SUMSQ(cA, cB, sq)
            sq = wave_sum_half(sq);
            const float inv = __builtin_amdgcn_rsqf(fmaf(sq, 1.f/64.f, 1e-5f));
            H2U inv2u; inv2u.p = __builtin_amdgcn_cvt_pkrtz(inv, inv);
            const half2t inv2 = inv2u.h;

            uint32_t yw[16];
#pragma unroll
            for (int m = 0; m < 16; ++m) {
                const f32x2 src = (m < 8) ? cA.d[m] : cB.d[m - 8];
                uint2 gb = gbtab[hi*16 + m];
                H2U x; x.p = __builtin_amdgcn_cvt_pkrtz(src[0], src[1]);
                H2U gg, bb; gg.u = gb.x; bb.u = gb.y;
                half2t gs = gg.h * inv2;
                half2t y = __builtin_elementwise_fma(x.h, gs, bb.h);
                y = __builtin_elementwise_max(y, z2h);
                H2U o; o.h = y; yw[m] = o.u;
            }

            C32U acc0, acc1;
            acc0.v = z16; acc1.v = z16;
#pragma unroll
            for (int c = 0; c < 2; ++c) {
                uint32_t w0, w1, w2, w3;
                half_swap(yw[4*c + 0], yw[4*c + 2], w0, w2);
                half_swap(yw[4*c + 1], yw[4*c + 3], w1, w3);
                FragU Bf; Bf.u[0] = w0; Bf.u[1] = w1; Bf.u[2] = w2; Bf.u[3] = w3;
                acc0.v = __builtin_amdgcn_mfma_f32_32x32x16_f16(a2[c].h, Bf.h, acc0.v, 0, 0, 0);
            }
#pragma unroll
            for (int c = 2; c < 4; ++c) {
                uint32_t w0, w1, w2, w3;
                half_swap(yw[4*c + 0], yw[4*c + 2], w0, w2);
                half_swap(yw[4*c + 1], yw[4*c + 3], w1, w3);
                FragU Bf; Bf.u[0] = w0; Bf.u[1] = w1; Bf.u[2] = w2; Bf.u[3] = w3;
                acc1.v = __builtin_amdgcn_mfma_f32_32x32x16_f16(a2[c].h, Bf.h, acc1.v, 0, 0, 0);
            }

            o0[0] = acc0.f[0] + acc1.f[0] + b2v[0];
            o1[0] = acc0.f[1] + acc1.f[1] + b2v[1];
            o2[0] = acc0.f[2] + acc1.f[2] + b2v[2];
            o3[0] = acc0.f[3] + acc1.f[3] + b2v[3];
            o0 += NN; o1 += NN; o2 += NN; o3 += NN;
        }
    }
}

extern "C" void kernel_launch(void* const* d_in, const int* in_sizes, int n_in,
                              void* d_out, int out_size, void* d_ws, size_t ws_size,
                              hipStream_t stream) {
    const float* rv    = (const float*)d_in[0];
    const float* W1    = (const float*)d_in[1];
    const float* b1    = (const float*)d_in[2];
    const float* gamma = (const float*)d_in[3];
    const float* beta  = (const float*)d_in[4];
    const float* W2    = (const float*)d_in[5];
    const float* b2    = (const float*)d_in[6];
    float* out = (float*)d_out;

    float* ws = (float*)d_ws;
    float* pt     = ws;                        // 8192 f32 (32 KB)
    float* w1tab  = ws + 8192;                 // 512 f32 (2 KB)
    uint4* w2pack = (uint4*)(ws + 8704);       // 1024 f32 (4 KB)
    uint2* gbtab  = (uint2*)(ws + 9728);       // 64 f32 (256 B)
    int*   flagp  = (int*)(ws + 9792);

    prep_kernel<<<9, 256, 0, stream>>>(rv, W1, b1, W2, gamma, beta,
                                       pt, w1tab, w2pack, gbtab, flagp);

    dim3 grid(NN / 128, NN / ITILE, NB);
    rpe_kernel<<<grid, 256, 0, stream>>>(pt, w1tab, w2pack, gbtab, flagp, b2, out);
}